// Round 1
// baseline (139.445 us; speedup 1.0000x reference)
//
#include <hip/hip_runtime.h>

// Loss_net: neural-ODE loss forward. R=8192 samples, D=3, N=10 RK4 super-steps.
// Decomposition: 8 lanes per sample; lane handles one (i,l) weight block of the
// 2 active hat-basis indices {k, k+1} x l in {0,1,2}; lanes 3,7 idle-compute zeros.
// Weights for the step are register-resident (loaded once per super-step).

#define R_    8192
#define M_    10
#define L_    3
#define HID_  5
#define D_    3
#define N_    10
#define H_    0.1f
#define LOG_2PI 1.8378770664093453f

__device__ __forceinline__ float fast_tanh(float x) {
    // tanh(x) = 1 - 2/(exp(2x)+1); exp via hw exp2, rcp via hw rcp (~1e-7 rel err)
    float e = __builtin_amdgcn_exp2f(x * 2.8853900817779268f); // 2*log2(e)*x
    return fmaf(-2.0f, __builtin_amdgcn_rcpf(e + 1.0f), 1.0f);
}

struct BlkW {
    float w1[HID_][D_];
    float b1v[HID_];
    float w2[D_][HID_];
    float b2v[D_];
    float g[HID_];     // G[h] = sum_d w2[d][h]*w1[h][d]  (divergence contraction)
};

__device__ __forceinline__ void load_blk(BlkW& B,
                                         const float* __restrict__ W1,
                                         const float* __restrict__ b1,
                                         const float* __restrict__ W2,
                                         const float* __restrict__ b2,
                                         int i, int l, bool act) {
    int blk = i * L_ + l;
    #pragma unroll
    for (int h = 0; h < HID_; ++h) {
        #pragma unroll
        for (int d = 0; d < D_; ++d)
            B.w1[h][d] = act ? W1[blk * HID_ * D_ + h * D_ + d] : 0.0f;
        B.b1v[h] = act ? b1[blk * HID_ + h] : 0.0f;
    }
    #pragma unroll
    for (int d = 0; d < D_; ++d) {
        #pragma unroll
        for (int h = 0; h < HID_; ++h)
            B.w2[d][h] = act ? W2[blk * D_ * HID_ + d * HID_ + h] : 0.0f;
        B.b2v[d] = act ? b2[blk * D_ + d] : 0.0f;
    }
    #pragma unroll
    for (int h = 0; h < HID_; ++h)
        B.g[h] = B.w2[0][h] * B.w1[h][0] + B.w2[1][h] * B.w1[h][1] + B.w2[2][h] * B.w1[h][2];
}

// v field eval: lane computes its block's contribution, then 8-lane xor reduce.
// All 8 lanes end with the full v vector.
__device__ __forceinline__ void v_eval8(const BlkW& B, float kf, int ii, float t,
                                        float x0, float x1, float x2,
                                        float& v0, float& v1, float& v2) {
    float w = fmaf(t, 10.0f, -kf);          // u - k  (may be ~0-eps or ~1+eps; fine)
    float p = ii ? w : (1.0f - w);          // my basis weight
    float a[HID_];
    #pragma unroll
    for (int h = 0; h < HID_; ++h) {
        float pre = fmaf(B.w1[h][0], x0, fmaf(B.w1[h][1], x1, fmaf(B.w1[h][2], x2, B.b1v[h])));
        a[h] = fast_tanh(pre);
    }
    float y0 = B.b2v[0], y1 = B.b2v[1], y2 = B.b2v[2];
    #pragma unroll
    for (int h = 0; h < HID_; ++h) {
        y0 = fmaf(B.w2[0][h], a[h], y0);
        y1 = fmaf(B.w2[1][h], a[h], y1);
        y2 = fmaf(B.w2[2][h], a[h], y2);
    }
    v0 = p * y0; v1 = p * y1; v2 = p * y2;
    #pragma unroll
    for (int m = 1; m < 8; m <<= 1) {
        v0 += __shfl_xor(v0, m);
        v1 += __shfl_xor(v1, m);
        v2 += __shfl_xor(v2, m);
    }
}

__device__ __forceinline__ float div_eval8(const BlkW& B, float kf, int ii, float t,
                                           float x0, float x1, float x2) {
    float w = fmaf(t, 10.0f, -kf);
    float p = ii ? w : (1.0f - w);
    float s = 0.0f;
    #pragma unroll
    for (int h = 0; h < HID_; ++h) {
        float pre = fmaf(B.w1[h][0], x0, fmaf(B.w1[h][1], x1, fmaf(B.w1[h][2], x2, B.b1v[h])));
        float th = fast_tanh(pre);
        s = fmaf(B.g[h], 1.0f - th * th, s);
    }
    float acc = p * s;
    #pragma unroll
    for (int m = 1; m < 8; m <<= 1) acc += __shfl_xor(acc, m);
    return acc;
}

// One RK4 substep (step = H/4) with K1 passed in; x updated in place.
__device__ __forceinline__ void rk4x(const BlkW& B, float kf, int ii, float t,
                                     float& x0, float& x1, float& x2,
                                     float k10, float k11, float k12) {
    const float s  = H_ * 0.25f;
    const float hs = s * 0.5f;
    float k20, k21, k22, k30, k31, k32, k40, k41, k42;
    v_eval8(B, kf, ii, t + hs, fmaf(hs, k10, x0), fmaf(hs, k11, x1), fmaf(hs, k12, x2), k20, k21, k22);
    v_eval8(B, kf, ii, t + hs, fmaf(hs, k20, x0), fmaf(hs, k21, x1), fmaf(hs, k22, x2), k30, k31, k32);
    v_eval8(B, kf, ii, t + s,  fmaf(s,  k30, x0), fmaf(s,  k31, x1), fmaf(s,  k32, x2), k40, k41, k42);
    const float c = s / 6.0f;
    x0 += c * (k10 + 2.0f * (k20 + k30) + k40);
    x1 += c * (k11 + 2.0f * (k21 + k31) + k41);
    x2 += c * (k12 + 2.0f * (k22 + k32) + k42);
}

__global__ void __launch_bounds__(256)
zero_ws_kernel(double* ws) {
    ws[0] = 0.0; ws[1] = 0.0;
}

__global__ void __launch_bounds__(256)
loss_main_kernel(const float* __restrict__ x,
                 const float* __restrict__ W1, const float* __restrict__ b1,
                 const float* __restrict__ W2, const float* __restrict__ b2,
                 double* __restrict__ ws) {
    int gid  = blockIdx.x * blockDim.x + threadIdx.x;
    int r    = gid >> 3;
    int sub  = gid & 7;       // 8 lanes per sample, aligned within the wave
    int ii   = sub >> 2;      // which of the 2 active basis indices
    int l    = sub & 3;       // block column; l==3 -> idle lane (zero weights)
    bool act = (l < 3);

    float X0 = x[r * 3 + 0];
    float X1 = x[r * 3 + 1];
    float X2 = x[r * 3 + 2];

    float lnRo = -0.5f * (3.0f * LOG_2PI + X0 * X0 + X1 * X1 + X2 * X2); // lnrho(x,0,1)
    float loss1p = 0.0f;
    float vA0 = 0.f, vA1 = 0.f, vA2 = 0.f;

    BlkW B;

    #pragma unroll 1
    for (int k = 0; k < N_; ++k) {
        float kf = (float)k;
        float tn = kf * H_;
        load_blk(B, W1, b1, W2, b2, k + ii, l, act);

        if (k == 0) v_eval8(B, kf, ii, tn, X0, X1, X2, vA0, vA1, vA2);

        // ---- 4 RK4 substeps, saving intermediate states for the div integrals
        float s00 = X0, s01 = X1, s02 = X2;                      // X0
        rk4x(B, kf, ii, tn, X0, X1, X2, vA0, vA1, vA2);          // -> X1
        float s10 = X0, s11 = X1, s12 = X2;

        float t1 = tn + 0.25f * H_;
        float q0, q1, q2;
        v_eval8(B, kf, ii, t1, X0, X1, X2, q0, q1, q2);
        rk4x(B, kf, ii, t1, X0, X1, X2, q0, q1, q2);             // -> X2
        float s20 = X0, s21 = X1, s22 = X2;

        float t2 = tn + 0.5f * H_;
        float vB0, vB1, vB2;
        v_eval8(B, kf, ii, t2, X0, X1, X2, vB0, vB1, vB2);
        rk4x(B, kf, ii, t2, X0, X1, X2, vB0, vB1, vB2);          // -> X3
        float s30 = X0, s31 = X1, s32 = X2;

        float t3 = tn + 0.75f * H_;
        v_eval8(B, kf, ii, t3, X0, X1, X2, q0, q1, q2);
        rk4x(B, kf, ii, t3, X0, X1, X2, q0, q1, q2);             // -> X4 (in X0..X2)

        float t4 = tn + H_;

        // ---- divergence integrals (two rk4_lnro calls share d2)
        float d0 = div_eval8(B, kf, ii, tn, s00, s01, s02);
        float d1 = div_eval8(B, kf, ii, t1, s10, s11, s12);
        float d2 = div_eval8(B, kf, ii, t2, s20, s21, s22);
        float d3 = div_eval8(B, kf, ii, t3, s30, s31, s32);
        float d4 = div_eval8(B, kf, ii, t4, X0, X1, X2);
        lnRo += (H_ / 12.0f) * (-d0 - 4.0f * d1 - d2)
              + (H_ / 12.0f) * (-d2 - 4.0f * d3 - d4);

        // ---- loss1 terms: v(X0,tn)=vA, v(X2,tn+H/2)=vB, v(X4,tn+H)=vC (-> next vA)
        float vC0, vC1, vC2;
        v_eval8(B, kf, ii, t4, X0, X1, X2, vC0, vC1, vC2);
        loss1p += (vA0 * vA0 + vA1 * vA1 + vA2 * vA2)
                + 4.0f * (vB0 * vB0 + vB1 * vB1 + vB2 * vB2)
                + (vC0 * vC0 + vC1 * vC1 + vC2 * vC2);
        vA0 = vC0; vA1 = vC1; vA2 = vC2;
    }

    // KL term per sample: lnRo - lnrho(X_final, 1, 1)
    float e0 = X0 - 1.0f, e1 = X1 - 1.0f, e2 = X2 - 1.0f;
    float lnr1 = -0.5f * (3.0f * LOG_2PI + e0 * e0 + e1 * e1 + e2 * e2);
    float klp = lnRo - lnr1;

    // per-sample values are replicated across the 8 lanes -> keep only lane 0 of each group
    if ((threadIdx.x & 7) != 0) { loss1p = 0.0f; klp = 0.0f; }
    #pragma unroll
    for (int off = 8; off < 64; off <<= 1) {
        loss1p += __shfl_xor(loss1p, off);
        klp    += __shfl_xor(klp, off);
    }
    if ((threadIdx.x & 63) == 0) {
        atomicAdd(&ws[0], (double)loss1p);
        atomicAdd(&ws[1], (double)klp);
    }
}

__global__ void __launch_bounds__(256)
finalize_kernel(const double* __restrict__ ws, float* __restrict__ out) {
    double l1 = (double)(H_) / (6.0 * (double)R_) * ws[0];
    double kl = ws[1] / (double)R_;
    float l1f = (float)l1;
    float klf = (float)kl;
    out[0] = l1f + klf;   // loss  (loss_F == 0)
    out[1] = l1f;         // loss1
    out[2] = klf;         // loss_KL
    out[3] = 0.0f;        // loss_F
}

extern "C" void kernel_launch(void* const* d_in, const int* in_sizes, int n_in,
                              void* d_out, int out_size, void* d_ws, size_t ws_size,
                              hipStream_t stream) {
    const float* x  = (const float*)d_in[0];
    const float* W1 = (const float*)d_in[1];
    const float* b1 = (const float*)d_in[2];
    const float* W2 = (const float*)d_in[3];
    const float* b2 = (const float*)d_in[4];
    double* ws = (double*)d_ws;       // ws[0]=sum loss1 partials, ws[1]=sum KL partials
    float* out = (float*)d_out;

    zero_ws_kernel<<<1, 1, 0, stream>>>(ws);
    // 8192 samples x 8 lanes = 65536 threads = 256 blocks x 256 -> 1 wave/SIMD chip-wide
    loss_main_kernel<<<256, 256, 0, stream>>>(x, W1, b1, W2, b2, ws);
    finalize_kernel<<<1, 1, 0, stream>>>(ws, out);
}

// Round 2
// 105.571 us; speedup vs baseline: 1.3209x; 1.3209x over previous
//
#include <hip/hip_runtime.h>

// Loss_net: neural-ODE loss forward. R=8192 samples, D=3, N=10 RK4 super-steps.
// 8 lanes per sample; lane handles one (i,l) weight block of the 2 active
// hat-basis indices {k,k+1} x l in {0,1,2}; lanes 3,7 compute zeros.
// 8-lane reductions use DPP (VALU pipe) instead of __shfl_xor (ds_bpermute /
// LDS pipe) -- the shfl latency sat directly on the serial RK4 chain.

#define R_    8192
#define M_    10
#define L_    3
#define HID_  5
#define D_    3
#define N_    10
#define H_    0.1f
#define LOG_2PI 1.8378770664093453f
#define NWAVES 1024   // 256 blocks x 256 threads / 64

__device__ __forceinline__ float fast_tanh(float x) {
    // tanh(x) = 1 - 2/(exp(2x)+1); exp via hw exp2, rcp via hw rcp (~1e-7 rel err)
    float e = __builtin_amdgcn_exp2f(x * 2.8853900817779268f); // 2*log2(e)*x
    return fmaf(-2.0f, __builtin_amdgcn_rcpf(e + 1.0f), 1.0f);
}

// --- DPP butterfly add over 8 contiguous lanes (all lanes get the sum) ---
// stages: xor1 (quad_perm [1,0,3,2]=0xB1), xor2 (quad_perm [2,3,0,1]=0x4E),
// i<->7-i (row_half_mirror=0x141). Mirror pairs each quad-sum with the other
// quad's sum, so the result is the full 8-lane total in every lane.
template<int CTRL>
__device__ __forceinline__ float dpp_addf(float v) {
    int t = __builtin_amdgcn_update_dpp(0, __float_as_int(v), CTRL, 0xF, 0xF, true);
    return v + __int_as_float(t);
}
__device__ __forceinline__ float red8(float v) {
    v = dpp_addf<0xB1>(v);
    v = dpp_addf<0x4E>(v);
    v = dpp_addf<0x141>(v);
    return v;
}

struct BlkW {
    float w1[HID_][D_];
    float b1v[HID_];
    float w2[D_][HID_];
    float b2v[D_];
    float g[HID_];     // G[h] = sum_d w2[d][h]*w1[h][d]  (divergence contraction)
};

__device__ __forceinline__ void load_blk(BlkW& B,
                                         const float* __restrict__ W1,
                                         const float* __restrict__ b1,
                                         const float* __restrict__ W2,
                                         const float* __restrict__ b2,
                                         int i, int l, bool act) {
    int blk = i * L_ + l;
    #pragma unroll
    for (int h = 0; h < HID_; ++h) {
        #pragma unroll
        for (int d = 0; d < D_; ++d)
            B.w1[h][d] = act ? W1[blk * HID_ * D_ + h * D_ + d] : 0.0f;
        B.b1v[h] = act ? b1[blk * HID_ + h] : 0.0f;
    }
    #pragma unroll
    for (int d = 0; d < D_; ++d) {
        #pragma unroll
        for (int h = 0; h < HID_; ++h)
            B.w2[d][h] = act ? W2[blk * D_ * HID_ + d * HID_ + h] : 0.0f;
        B.b2v[d] = act ? b2[blk * D_ + d] : 0.0f;
    }
    #pragma unroll
    for (int h = 0; h < HID_; ++h)
        B.g[h] = B.w2[0][h] * B.w1[h][0] + B.w2[1][h] * B.w1[h][1] + B.w2[2][h] * B.w1[h][2];
}

// v field eval: lane computes its block's contribution, then 8-lane DPP reduce.
// All 8 lanes end with the full v vector.
__device__ __forceinline__ void v_eval8(const BlkW& B, float kf, int ii, float t,
                                        float x0, float x1, float x2,
                                        float& v0, float& v1, float& v2) {
    float w = fmaf(t, 10.0f, -kf);          // u - k
    float p = ii ? w : (1.0f - w);          // my basis weight
    float a[HID_];
    #pragma unroll
    for (int h = 0; h < HID_; ++h) {
        float pre = fmaf(B.w1[h][0], x0, fmaf(B.w1[h][1], x1, fmaf(B.w1[h][2], x2, B.b1v[h])));
        a[h] = fast_tanh(pre);
    }
    float y0 = B.b2v[0], y1 = B.b2v[1], y2 = B.b2v[2];
    #pragma unroll
    for (int h = 0; h < HID_; ++h) {
        y0 = fmaf(B.w2[0][h], a[h], y0);
        y1 = fmaf(B.w2[1][h], a[h], y1);
        y2 = fmaf(B.w2[2][h], a[h], y2);
    }
    v0 = red8(p * y0);
    v1 = red8(p * y1);
    v2 = red8(p * y2);
}

__device__ __forceinline__ float div_eval8(const BlkW& B, float kf, int ii, float t,
                                           float x0, float x1, float x2) {
    float w = fmaf(t, 10.0f, -kf);
    float p = ii ? w : (1.0f - w);
    float s = 0.0f;
    #pragma unroll
    for (int h = 0; h < HID_; ++h) {
        float pre = fmaf(B.w1[h][0], x0, fmaf(B.w1[h][1], x1, fmaf(B.w1[h][2], x2, B.b1v[h])));
        float th = fast_tanh(pre);
        s = fmaf(B.g[h], 1.0f - th * th, s);
    }
    return red8(p * s);
}

// One RK4 substep (step = H/4) with K1 passed in; x updated in place.
__device__ __forceinline__ void rk4x(const BlkW& B, float kf, int ii, float t,
                                     float& x0, float& x1, float& x2,
                                     float k10, float k11, float k12) {
    const float s  = H_ * 0.25f;
    const float hs = s * 0.5f;
    float k20, k21, k22, k30, k31, k32, k40, k41, k42;
    v_eval8(B, kf, ii, t + hs, fmaf(hs, k10, x0), fmaf(hs, k11, x1), fmaf(hs, k12, x2), k20, k21, k22);
    v_eval8(B, kf, ii, t + hs, fmaf(hs, k20, x0), fmaf(hs, k21, x1), fmaf(hs, k22, x2), k30, k31, k32);
    v_eval8(B, kf, ii, t + s,  fmaf(s,  k30, x0), fmaf(s,  k31, x1), fmaf(s,  k32, x2), k40, k41, k42);
    const float c = s / 6.0f;
    x0 += c * (k10 + 2.0f * (k20 + k30) + k40);
    x1 += c * (k11 + 2.0f * (k21 + k31) + k41);
    x2 += c * (k12 + 2.0f * (k22 + k32) + k42);
}

__global__ void __launch_bounds__(256)
loss_main_kernel(const float* __restrict__ x,
                 const float* __restrict__ W1, const float* __restrict__ b1,
                 const float* __restrict__ W2, const float* __restrict__ b2,
                 double* __restrict__ ws) {
    int gid  = blockIdx.x * blockDim.x + threadIdx.x;
    int r    = gid >> 3;
    int sub  = gid & 7;       // 8 lanes per sample, aligned within the wave
    int ii   = sub >> 2;      // which of the 2 active basis indices
    int l    = sub & 3;       // block column; l==3 -> idle lane (zero weights)
    bool act = (l < 3);

    float X0 = x[r * 3 + 0];
    float X1 = x[r * 3 + 1];
    float X2 = x[r * 3 + 2];

    float lnRo = -0.5f * (3.0f * LOG_2PI + X0 * X0 + X1 * X1 + X2 * X2); // lnrho(x,0,1)
    float loss1p = 0.0f;
    float vA0 = 0.f, vA1 = 0.f, vA2 = 0.f;

    BlkW B;

    #pragma unroll 1
    for (int k = 0; k < N_; ++k) {
        float kf = (float)k;
        float tn = kf * H_;
        load_blk(B, W1, b1, W2, b2, k + ii, l, act);

        if (k == 0) v_eval8(B, kf, ii, tn, X0, X1, X2, vA0, vA1, vA2);

        // ---- 4 RK4 substeps, saving intermediate states for the div integrals
        float s00 = X0, s01 = X1, s02 = X2;                      // X0
        rk4x(B, kf, ii, tn, X0, X1, X2, vA0, vA1, vA2);          // -> X1
        float s10 = X0, s11 = X1, s12 = X2;

        float t1 = tn + 0.25f * H_;
        float q0, q1, q2;
        v_eval8(B, kf, ii, t1, X0, X1, X2, q0, q1, q2);
        rk4x(B, kf, ii, t1, X0, X1, X2, q0, q1, q2);             // -> X2
        float s20 = X0, s21 = X1, s22 = X2;

        float t2 = tn + 0.5f * H_;
        float vB0, vB1, vB2;
        v_eval8(B, kf, ii, t2, X0, X1, X2, vB0, vB1, vB2);
        rk4x(B, kf, ii, t2, X0, X1, X2, vB0, vB1, vB2);          // -> X3
        float s30 = X0, s31 = X1, s32 = X2;

        float t3 = tn + 0.75f * H_;
        v_eval8(B, kf, ii, t3, X0, X1, X2, q0, q1, q2);
        rk4x(B, kf, ii, t3, X0, X1, X2, q0, q1, q2);             // -> X4 (in X0..X2)

        float t4 = tn + H_;

        // ---- divergence integrals (two rk4_lnro calls share d2)
        float d0 = div_eval8(B, kf, ii, tn, s00, s01, s02);
        float d1 = div_eval8(B, kf, ii, t1, s10, s11, s12);
        float d2 = div_eval8(B, kf, ii, t2, s20, s21, s22);
        float d3 = div_eval8(B, kf, ii, t3, s30, s31, s32);
        float d4 = div_eval8(B, kf, ii, t4, X0, X1, X2);
        lnRo += (H_ / 12.0f) * (-d0 - 4.0f * d1 - d2)
              + (H_ / 12.0f) * (-d2 - 4.0f * d3 - d4);

        // ---- loss1 terms: v(X0,tn)=vA, v(X2,tn+H/2)=vB, v(X4,tn+H)=vC (-> next vA)
        float vC0, vC1, vC2;
        v_eval8(B, kf, ii, t4, X0, X1, X2, vC0, vC1, vC2);
        loss1p += (vA0 * vA0 + vA1 * vA1 + vA2 * vA2)
                + 4.0f * (vB0 * vB0 + vB1 * vB1 + vB2 * vB2)
                + (vC0 * vC0 + vC1 * vC1 + vC2 * vC2);
        vA0 = vC0; vA1 = vC1; vA2 = vC2;
    }

    // KL term per sample: lnRo - lnrho(X_final, 1, 1)
    float e0 = X0 - 1.0f, e1 = X1 - 1.0f, e2 = X2 - 1.0f;
    float lnr1 = -0.5f * (3.0f * LOG_2PI + e0 * e0 + e1 * e1 + e2 * e2);
    float klp = lnRo - lnr1;

    // per-sample values are replicated across the 8 lanes -> keep lane 0 of each group
    if ((threadIdx.x & 7) != 0) { loss1p = 0.0f; klp = 0.0f; }
    #pragma unroll
    for (int off = 8; off < 64; off <<= 1) {      // once per kernel: shfl is fine here
        loss1p += __shfl_xor(loss1p, off);
        klp    += __shfl_xor(klp, off);
    }
    // every wave writes its partial unconditionally -> no zero-init kernel needed
    if ((threadIdx.x & 63) == 0) {
        int wid = gid >> 6;
        ws[wid]          = (double)loss1p;
        ws[NWAVES + wid] = (double)klp;
    }
}

__global__ void __launch_bounds__(64)
finalize_kernel(const double* __restrict__ ws, float* __restrict__ out) {
    // single wave: each lane sums 16 partials of each accumulator, then reduce
    int lane = threadIdx.x;
    double l1 = 0.0, kl = 0.0;
    #pragma unroll
    for (int j = 0; j < NWAVES / 64; ++j) {
        l1 += ws[lane + j * 64];
        kl += ws[NWAVES + lane + j * 64];
    }
    #pragma unroll
    for (int off = 1; off < 64; off <<= 1) {
        l1 += __shfl_xor(l1, off);
        kl += __shfl_xor(kl, off);
    }
    if (lane == 0) {
        double l1s = (double)H_ / (6.0 * (double)R_) * l1;
        double kls = kl / (double)R_;
        float l1f = (float)l1s;
        float klf = (float)kls;
        out[0] = l1f + klf;   // loss  (loss_F == 0)
        out[1] = l1f;         // loss1
        out[2] = klf;         // loss_KL
        out[3] = 0.0f;        // loss_F
    }
}

extern "C" void kernel_launch(void* const* d_in, const int* in_sizes, int n_in,
                              void* d_out, int out_size, void* d_ws, size_t ws_size,
                              hipStream_t stream) {
    const float* x  = (const float*)d_in[0];
    const float* W1 = (const float*)d_in[1];
    const float* b1 = (const float*)d_in[2];
    const float* W2 = (const float*)d_in[3];
    const float* b2 = (const float*)d_in[4];
    double* ws = (double*)d_ws;   // [0..1023]=loss1 wave partials, [1024..2047]=KL
    float* out = (float*)d_out;

    // 8192 samples x 8 lanes = 65536 threads = 256 blocks x 256 -> 1 wave/SIMD chip-wide
    loss_main_kernel<<<256, 256, 0, stream>>>(x, W1, b1, W2, b2, ws);
    finalize_kernel<<<1, 64, 0, stream>>>(ws, out);
}